// Round 9
// baseline (168.483 us; speedup 1.0000x reference)
//
#include <hip/hip_runtime.h>

// Workspace float offsets
#define F_XM    0u          // bf16 xm[8][4096][256]      -> 4,194,304 f
#define F_XG    4194304u    // bf16 xg[8][2][4096][256]   -> 8,388,608 f
#define F_Y     4194304u    // bf16 y[8][2][4096][128] aliases xg (dead after k_g)
#define F_TH    12582912u   // bf16 theta[8][4096][128]   -> 2,097,152 f
#define F_PHIB  14680064u   // bf16 phi[8][1024][128]     ->   524,288 f
#define F_GB    15204352u   // bf16 g[8][256][1024]       -> 1,048,576 f
// total 16,252,928 floats = 65.0 MB

typedef __attribute__((ext_vector_type(4))) float f32x4;
typedef __attribute__((ext_vector_type(8))) short bf16x8;

__device__ __forceinline__ unsigned short f2bf(float f) {
  union { unsigned int i; float f; } x; x.f = f;
  unsigned int r = x.i + 0x7fffu + ((x.i >> 16) & 1u);
  return (unsigned short)(r >> 16);
}
__device__ __forceinline__ unsigned int pk2(float a, float b) {
  return (unsigned int)f2bf(a) | ((unsigned int)f2bf(b) << 16);
}
__device__ __forceinline__ void gload_lds16(const void* g, void* l) {
  __builtin_amdgcn_global_load_lds(
      (const __attribute__((address_space(1))) unsigned int*)g,
      (__attribute__((address_space(3))) unsigned int*)l, 16, 0, 0);
}

// ---------------------------------------------------------------------------
// Prep: x f32 [b][512][4096] -> bf16 xm[b][n][256] (mean over group pair) and
// xg[b][gr][n][256] (K-contiguous layouts for the MFMA GEMMs).
// ---------------------------------------------------------------------------
__global__ __launch_bounds__(256)
void k_prep(const float* __restrict__ x, float* __restrict__ ws) {
  const int nt = blockIdx.x, ct = blockIdx.y, b = blockIdx.z;
  const int n0 = nt * 256, c0 = ct * 64;
  const int tid = threadIdx.x;
  __shared__ uint4 ldsb[4096];               // 64 KB: f32 [64 c][1024B] swz
  char* lds = (char*)ldsb;
  {
    const int c = tid >> 2;
    const int nch = (tid & 3) * 64;
    const float* src = x + ((size_t)(b * 512 + c0 + c)) * 4096 + n0 + nch;
    char* row = lds + c * 1024;
    const int sw = (c & 7) << 4;
    const int bb = nch * 4;
#pragma unroll
    for (int k = 0; k < 16; ++k)
      *(uint4*)(row + ((bb + 16 * k) ^ sw)) = ((const uint4*)src)[k];
  }
  __syncthreads();
  {
    const int n = tid;
    unsigned int u0[16], u1[16], um[16];
#pragma unroll
    for (int jc = 0; jc < 4; ++jc) {
      float v[16];
#pragma unroll
      for (int cc = 0; cc < 16; ++cc) {
        const int c = 16 * jc + cc;
        v[cc] = *(const float*)(lds + c * 1024 + ((n * 4) ^ ((c & 7) << 4)));
      }
#pragma unroll
      for (int s = 0; s < 4; ++s) {
        u0[4 * jc + s] = pk2(v[4 * s], v[4 * s + 2]);
        u1[4 * jc + s] = pk2(v[4 * s + 1], v[4 * s + 3]);
        um[4 * jc + s] = pk2(0.5f * (v[4 * s] + v[4 * s + 1]),
                             0.5f * (v[4 * s + 2] + v[4 * s + 3]));
      }
    }
    unsigned short* xm = (unsigned short*)(ws + F_XM);
    unsigned short* xg = (unsigned short*)(ws + F_XG);
    uint4* d0 = (uint4*)(xg + (((size_t)(b * 2 + 0) * 4096) + n0 + n) * 256 + (c0 >> 1));
    uint4* d1 = (uint4*)(xg + (((size_t)(b * 2 + 1) * 4096) + n0 + n) * 256 + (c0 >> 1));
    uint4* dm = (uint4*)(xm + ((size_t)(b * 4096) + n0 + n) * 256 + (c0 >> 1));
#pragma unroll
    for (int s = 0; s < 4; ++s) {
      d0[s] = make_uint4(u0[4 * s], u0[4 * s + 1], u0[4 * s + 2], u0[4 * s + 3]);
      d1[s] = make_uint4(u1[4 * s], u1[4 * s + 1], u1[4 * s + 2], u1[4 * s + 3]);
      dm[s] = make_uint4(um[4 * s], um[4 * s + 1], um[4 * s + 2], um[4 * s + 3]);
    }
  }
}

// ---------------------------------------------------------------------------
// theta & phi projections from xm (K=256). Out tile 128 o x 128 n, 4 waves.
// ot=0: theta[b][n][o] bf16 (LDS transpose). ot=1: pooled phiB[b][m][o] bf16.
// ---------------------------------------------------------------------------
__global__ __launch_bounds__(256)
void k_proj_mfma(const float* __restrict__ tw, const float* __restrict__ tb,
                 const float* __restrict__ pw, const float* __restrict__ pb,
                 float* __restrict__ ws) {
  const int nt = blockIdx.x, ot = blockIdx.y, b = blockIdx.z;
  const int n0 = nt * 128;
  const int tid = threadIdx.x;
  const int w = tid >> 6, lane = tid & 63, q = lane >> 4, col = lane & 15;
  const float* W = ot ? pw : tw;
  const float* bias = ot ? pb : tb;
  const unsigned short* xm = (const unsigned short*)(ws + F_XM);

  __shared__ uint4 ldsb[4096];               // 64 KB
  char* Ws = (char*)ldsb;                    // [128 o][128B] swz
  char* Xs = (char*)ldsb + 16384;            // [128 n][128B] swz

  f32x4 acc[2][8];
#pragma unroll
  for (int h = 0; h < 2; ++h)
#pragma unroll
    for (int j = 0; j < 8; ++j) acc[h][j] = (f32x4){0.f, 0.f, 0.f, 0.f};

  const int ro = tid >> 1, haf = tid & 1;
  for (int ks = 0; ks < 4; ++ks) {
    __syncthreads();
    {
      const float* src = W + (size_t)ro * 256 + ks * 64 + haf * 32;
      char* row = Ws + ro * 128;
      const int sw = (ro & 7) << 4;
#pragma unroll
      for (int jj = 0; jj < 4; ++jj) {
        float4 a = ((const float4*)src)[2 * jj];
        float4 c4 = ((const float4*)src)[2 * jj + 1];
        uint4 pk;
        pk.x = pk2(a.x, a.y);  pk.y = pk2(a.z, a.w);
        pk.z = pk2(c4.x, c4.y); pk.w = pk2(c4.z, c4.w);
        *(uint4*)(row + ((haf * 64 + 16 * jj) ^ sw)) = pk;
      }
    }
    {
      const unsigned short* src = xm + ((size_t)(b * 4096) + n0 + ro) * 256 + ks * 64 + haf * 32;
      char* row = Xs + ro * 128;
      const int sw = (ro & 7) << 4;
#pragma unroll
      for (int jj = 0; jj < 4; ++jj)
        *(uint4*)(row + ((haf * 64 + 16 * jj) ^ sw)) = ((const uint4*)src)[jj];
    }
    __syncthreads();
#pragma unroll
    for (int c = 0; c < 2; ++c) {
      bf16x8 af[2], bfr[8];
#pragma unroll
      for (int h = 0; h < 2; ++h) {
        const int r = 32 * w + 16 * h + col;
        af[h] = *(const bf16x8*)(Ws + r * 128 + ((64 * c + 16 * q) ^ ((r & 7) << 4)));
      }
#pragma unroll
      for (int j = 0; j < 8; ++j) {
        const int r = 16 * j + col;
        bfr[j] = *(const bf16x8*)(Xs + r * 128 + ((64 * c + 16 * q) ^ ((r & 7) << 4)));
      }
#pragma unroll
      for (int h = 0; h < 2; ++h)
#pragma unroll
        for (int j = 0; j < 8; ++j)
          acc[h][j] = __builtin_amdgcn_mfma_f32_16x16x32_bf16(af[h], bfr[j], acc[h][j], 0, 0, 0);
    }
  }

  float bs[2][4];
#pragma unroll
  for (int h = 0; h < 2; ++h) {
    const int o0 = 32 * w + 16 * h + 4 * q;
#pragma unroll
    for (int r = 0; r < 4; ++r) bs[h][r] = bias[o0 + r];
  }

  if (ot == 0) {
    char* trb = (char*)ldsb + 32768;         // [128 n][256B] swz, fresh region
#pragma unroll
    for (int h = 0; h < 2; ++h) {
      const int o0 = 32 * w + 16 * h + 4 * q;
#pragma unroll
      for (int j = 0; j < 8; ++j) {
        const int n = 16 * j + col;
        uint2 pkk = make_uint2(pk2(acc[h][j][0] + bs[h][0], acc[h][j][1] + bs[h][1]),
                               pk2(acc[h][j][2] + bs[h][2], acc[h][j][3] + bs[h][3]));
        *(uint2*)(trb + n * 256 + ((2 * o0) ^ ((n & 7) << 4))) = pkk;
      }
    }
    __syncthreads();
    {
      const int n = tid >> 1, h2 = tid & 1;
      unsigned short* dst = (unsigned short*)(ws + F_TH) + ((size_t)(b * 4096) + n0 + n) * 128 + h2 * 64;
      const char* row = trb + n * 256;
      const int sw = (n & 7) << 4;
#pragma unroll
      for (int k = 0; k < 8; ++k)
        ((uint4*)dst)[k] = *(const uint4*)(row + ((128 * h2 + 16 * k) ^ sw));
    }
  } else {
    const int mb = (nt >> 3) * 256 + (nt & 7) * 32;
    unsigned short* phiB = (unsigned short*)(ws + F_PHIB);
#pragma unroll
    for (int h = 0; h < 2; ++h) {
      const int o0 = 32 * w + 16 * h + 4 * q;
#pragma unroll
      for (int jj = 0; jj < 4; ++jj) {
        const int j = (jj >> 1) * 4 + (jj & 1);   // {0,1,4,5}
        f32x4 pm;
#pragma unroll
        for (int r = 0; r < 4; ++r)
          pm[r] = fmaxf(acc[h][j][r], acc[h][j + 2][r]);
#pragma unroll
        for (int r = 0; r < 4; ++r)
          pm[r] = fmaxf(pm[r], __shfl_xor(pm[r], 1));
        if ((col & 1) == 0) {
          const int vp = 8 * (j & 1) + (col >> 1);
          const int m = mb + 16 * (j >> 2) + vp;
          uint2 pkk = make_uint2(pk2(pm[0] + bs[h][0], pm[1] + bs[h][1]),
                                 pk2(pm[2] + bs[h][2], pm[3] + bs[h][3]));
          *(uint2*)(phiB + ((size_t)(b * 1024) + m) * 128 + o0) = pkk;
        }
      }
    }
  }
}

// ---------------------------------------------------------------------------
// g projection from xg (per group, K=256), fused pool -> gB[b][d=2o+gr][m].
// ---------------------------------------------------------------------------
__global__ __launch_bounds__(256)
void k_g_mfma(const float* __restrict__ gw, const float* __restrict__ gb,
              float* __restrict__ ws) {
  const int nt = blockIdx.x, gr = blockIdx.y, b = blockIdx.z;
  const int n0 = nt * 128;
  const int tid = threadIdx.x;
  const int w = tid >> 6, lane = tid & 63, q = lane >> 4, col = lane & 15;
  const unsigned short* xg = (const unsigned short*)(ws + F_XG);

  __shared__ uint4 ldsb[4096];
  char* Ws = (char*)ldsb;
  char* Xs = (char*)ldsb + 16384;

  f32x4 acc[2][8];
#pragma unroll
  for (int h = 0; h < 2; ++h)
#pragma unroll
    for (int j = 0; j < 8; ++j) acc[h][j] = (f32x4){0.f, 0.f, 0.f, 0.f};

  const int ro = tid >> 1, haf = tid & 1;
  for (int ks = 0; ks < 4; ++ks) {
    __syncthreads();
    {
      const float* src = gw + (size_t)ro * 256 + ks * 64 + haf * 32;
      char* row = Ws + ro * 128;
      const int sw = (ro & 7) << 4;
#pragma unroll
      for (int jj = 0; jj < 4; ++jj) {
        float4 a = ((const float4*)src)[2 * jj];
        float4 c4 = ((const float4*)src)[2 * jj + 1];
        uint4 pk;
        pk.x = pk2(a.x, a.y);  pk.y = pk2(a.z, a.w);
        pk.z = pk2(c4.x, c4.y); pk.w = pk2(c4.z, c4.w);
        *(uint4*)(row + ((haf * 64 + 16 * jj) ^ sw)) = pk;
      }
    }
    {
      const unsigned short* src = xg + (((size_t)(b * 2 + gr)) * 4096 + n0 + ro) * 256 + ks * 64 + haf * 32;
      char* row = Xs + ro * 128;
      const int sw = (ro & 7) << 4;
#pragma unroll
      for (int jj = 0; jj < 4; ++jj)
        *(uint4*)(row + ((haf * 64 + 16 * jj) ^ sw)) = ((const uint4*)src)[jj];
    }
    __syncthreads();
#pragma unroll
    for (int c = 0; c < 2; ++c) {
      bf16x8 af[2], bfr[8];
#pragma unroll
      for (int h = 0; h < 2; ++h) {
        const int r = 32 * w + 16 * h + col;
        af[h] = *(const bf16x8*)(Ws + r * 128 + ((64 * c + 16 * q) ^ ((r & 7) << 4)));
      }
#pragma unroll
      for (int j = 0; j < 8; ++j) {
        const int r = 16 * j + col;
        bfr[j] = *(const bf16x8*)(Xs + r * 128 + ((64 * c + 16 * q) ^ ((r & 7) << 4)));
      }
#pragma unroll
      for (int h = 0; h < 2; ++h)
#pragma unroll
        for (int j = 0; j < 8; ++j)
          acc[h][j] = __builtin_amdgcn_mfma_f32_16x16x32_bf16(af[h], bfr[j], acc[h][j], 0, 0, 0);
    }
  }

  const int mb = (nt >> 3) * 256 + (nt & 7) * 32;
  char* pt = (char*)ldsb + 32768;            // [128 o][80B], fresh region
#pragma unroll
  for (int h = 0; h < 2; ++h) {
    const int o0 = 32 * w + 16 * h + 4 * q;
#pragma unroll
    for (int jj = 0; jj < 4; ++jj) {
      const int j = (jj >> 1) * 4 + (jj & 1);
      f32x4 pm;
#pragma unroll
      for (int r = 0; r < 4; ++r)
        pm[r] = fmaxf(acc[h][j][r], acc[h][j + 2][r]);
#pragma unroll
      for (int r = 0; r < 4; ++r)
        pm[r] = fmaxf(pm[r], __shfl_xor(pm[r], 1));
      if ((col & 1) == 0) {
        const int ml = 16 * (j >> 2) + 8 * (j & 1) + (col >> 1);
#pragma unroll
        for (int r = 0; r < 4; ++r)
          *(unsigned short*)(pt + (o0 + r) * 80 + ml * 2) = f2bf(pm[r] + gb[o0 + r]);
      }
    }
  }
  __syncthreads();
  if (tid < 128) {
    const int o = tid;
    const char* row = pt + o * 80;
    unsigned short* dst = (unsigned short*)(ws + F_GB) + ((size_t)(b * 256) + 2 * o + gr) * 1024 + mb;
#pragma unroll
    for (int k = 0; k < 4; ++k)
      ((uint4*)dst)[k] = *(const uint4*)(row + 16 * k);
  }
}

// ---------------------------------------------------------------------------
// MFMA flash attention v6: dbuf global_load_lds staging, K tiles of 32 m
// (8KB x2), V tiles of 64 m with 128B rows (32KB x2, R5's measured-low-
// conflict layout), P repack fully in-register via 8 __shfl (no LDS).
// One barrier per iteration. LDS 80KB -> 2 blocks/CU.
// ---------------------------------------------------------------------------
#define KVB 32
#define NIT 32
__global__ __launch_bounds__(256)
void k_attn_mfma(float* __restrict__ ws) {
  const int b = blockIdx.x;          // 8 batches -> 8 XCDs (round-robin)
  const int n0 = blockIdx.y * 64;
  const int tid = threadIdx.x;
  const int w = tid >> 6;
  const int lane = tid & 63;
  const int q = lane >> 4;
  const int col = lane & 15;
  const int ksw = (col & 7) << 4;

  __shared__ char lds[81920];
  // kbuf[2]: 2 x 8KB  @ 0      (K tile [32 m][256B], row-swz ((m&7)<<4))
  // vbuf[2]: 2 x 32KB @ 16384  (V^T pair-tile [256 d][128B], row-swz ((d&7)<<4))

  const unsigned short* thetaB = (const unsigned short*)(ws + F_TH);
  const char* phiBb = (const char*)((const unsigned short*)(ws + F_PHIB) + (size_t)b * 1024 * 128);
  const char* gBb   = (const char*)((const unsigned short*)(ws + F_GB) + (size_t)b * 256 * 1024);
  unsigned short* yB = (unsigned short*)(ws + F_Y);

  // staging geometry (pre-swizzled global SOURCE, linear LDS dest = base+lane*16)
  const int kr0 = lane >> 4;               // K: row within 4-row chunk
  const int kso = (lane & 15) * 16;        // K: byte within 256B row
  const int vr0 = lane >> 3;               // V: row within 8-row chunk
  const int vso = (lane & 7) * 16;         // V: byte within 128B row

  bf16x8 qf[4];
  {
    const unsigned short* qp = thetaB + ((size_t)(b * 4096 + n0 + 16 * w + col)) * 128 + 8 * q;
#pragma unroll
    for (int c = 0; c < 4; ++c) qf[c] = *(const bf16x8*)(qp + 32 * c);
  }

  f32x4 ot[16];
#pragma unroll
  for (int t = 0; t < 16; ++t) ot[t] = (f32x4){0.f, 0.f, 0.f, 0.f};
  float mrun = -1e30f, lsum = 0.f;

  // prologue: K tile 0 -> kbuf0, V pair 0 -> vbuf0
#pragma unroll
  for (int j = 0; j < 2; ++j) {
    const int c = w * 2 + j;
    const int r = 4 * c + kr0;
    gload_lds16(phiBb + (size_t)r * 256 + (kso ^ ((r & 7) << 4)), lds + c * 1024);
  }
#pragma unroll
  for (int j = 0; j < 8; ++j) {
    const int d = 64 * w + 8 * j + vr0;
    gload_lds16(gBb + (size_t)d * 2048 + (vso ^ ((d & 7) << 4)),
                lds + 16384 + (64 * w + 8 * j) * 128);
  }
  __syncthreads();

  for (int mt = 0; mt < NIT; ++mt) {
    char* ktc = lds + (mt & 1) * 8192;
    char* vtc = lds + 16384 + ((mt >> 1) & 1) * 32768;
    const int par = mt & 1;

    // stage next K tile (async; completes by end-of-iter barrier)
    if (mt + 1 < NIT) {
      const size_t moff = (size_t)(mt + 1) * KVB;
#pragma unroll
      for (int j = 0; j < 2; ++j) {
        const int c = w * 2 + j;
        const int r = 4 * c + kr0;
        gload_lds16(phiBb + (moff + r) * 256 + (kso ^ ((r & 7) << 4)),
                    lds + (((mt & 1) ^ 1)) * 8192 + c * 1024);
      }
    }
    // stage next V pair at pair boundary
    if (par == 0 && mt + 2 < NIT) {
      const size_t pm0 = (size_t)((mt >> 1) + 1) * 64;
#pragma unroll
      for (int j = 0; j < 8; ++j) {
        const int d = 64 * w + 8 * j + vr0;
        gload_lds16(gBb + (size_t)d * 2048 + pm0 * 2 + (vso ^ ((d & 7) << 4)),
                    lds + 16384 + ((((mt >> 1) & 1) ^ 1)) * 32768 + (64 * w + 8 * j) * 128);
      }
    }

    // S^T = K . Q^T  (st[s]: m-local 16s..16s+15, n = col)
    f32x4 st[2];
#pragma unroll
    for (int s = 0; s < 2; ++s) st[s] = (f32x4){0.f, 0.f, 0.f, 0.f};
    __builtin_amdgcn_s_setprio(1);
#pragma unroll
    for (int c = 0; c < 4; ++c)
#pragma unroll
      for (int s = 0; s < 2; ++s) {
        const bf16x8 kf = *(const bf16x8*)(ktc + (16 * s + col) * 256 +
                                           ((64 * c + 16 * q) ^ ksw));
        st[s] = __builtin_amdgcn_mfma_f32_16x16x32_bf16(kf, qf[c], st[s], 0, 0, 0);
      }
    __builtin_amdgcn_s_setprio(0);

    // online softmax with defer-max (threshold 8)
    float pmax = -1e30f;
#pragma unroll
    for (int s = 0; s < 2; ++s)
#pragma unroll
      for (int r = 0; r < 4; ++r) pmax = fmaxf(pmax, st[s][r]);
    pmax = fmaxf(pmax, __shfl_xor(pmax, 16));
    pmax = fmaxf(pmax, __shfl_xor(pmax, 32));
    if (!__all(pmax - mrun <= 8.f)) {
      const float mnew = fmaxf(mrun, pmax);
      const float scl = __expf(mrun - mnew);
      mrun = mnew;
      lsum *= scl;
#pragma unroll
      for (int t = 0; t < 16; ++t) {
        ot[t][0] *= scl; ot[t][1] *= scl; ot[t][2] *= scl; ot[t][3] *= scl;
      }
    }
    float rsum = 0.f;
#pragma unroll
    for (int s = 0; s < 2; ++s)
#pragma unroll
      for (int r = 0; r < 4; ++r) {
        st[s][r] = __expf(st[s][r] - mrun);
        rsum += st[s][r];
      }
    rsum += __shfl_xor(rsum, 16);
    rsum += __shfl_xor(rsum, 32);
    lsum += rsum;

    // P repack entirely in-register: lane (q',col) needs P[8q'..8q'+7][col].
    // Sources: lanes col+16*((2q')&3) and col+16*((2q'+1)&3); regs u0/u1 for
    // q'<2 (s=0 half, m<16), u2/u3 for q'>=2 (s=1 half, m>=16).
    {
      const unsigned pu0 = pk2(st[0][0], st[0][1]);
      const unsigned pu1 = pk2(st[0][2], st[0][3]);
      const unsigned pu2 = pk2(st[1][0], st[1][1]);
      const unsigned pu3 = pk2(st[1][2], st[1][3]);
      const int src0 = col + 16 * ((2 * q) & 3);
      const int src1 = col + 16 * ((2 * q + 1) & 3);
      const unsigned lo0 = (unsigned)__shfl((int)pu0, src0);
      const unsigned lo1 = (unsigned)__shfl((int)pu1, src0);
      const unsigned lo2 = (unsigned)__shfl((int)pu0, src1);
      const unsigned lo3 = (unsigned)__shfl((int)pu1, src1);
      const unsigned hi0 = (unsigned)__shfl((int)pu2, src0);
      const unsigned hi1 = (unsigned)__shfl((int)pu3, src0);
      const unsigned hi2 = (unsigned)__shfl((int)pu2, src1);
      const unsigned hi3 = (unsigned)__shfl((int)pu3, src1);
      union { unsigned u[4]; bf16x8 v; } pfu;
      const bool hs = (q >= 2);
      pfu.u[0] = hs ? hi0 : lo0;
      pfu.u[1] = hs ? hi1 : lo1;
      pfu.u[2] = hs ? hi2 : lo2;
      pfu.u[3] = hs ? hi3 : lo3;

      // O^T += V^T . P^T  (V pair-tile: 64B half selected by par)
      __builtin_amdgcn_s_setprio(1);
#pragma unroll
      for (int t = 0; t < 16; ++t) {
        const int d = 16 * t + col;
        const bf16x8 vf = *(const bf16x8*)(vtc + d * 128 +
                                           ((64 * par + 16 * q) ^ ((d & 7) << 4)));
        ot[t] = __builtin_amdgcn_mfma_f32_16x16x32_bf16(vf, pfu.v, ot[t], 0, 0, 0);
      }
      __builtin_amdgcn_s_setprio(0);
    }

    __syncthreads();   // staged tiles complete + all waves done with cur bufs
  }

  // epilogue: y[b][gr][n][i] bf16. d = 16t+4q+r -> gr=r&1, i = 8t+2q+(r>>1)
  const float inv = 1.f / lsum;
  char* yt = lds;                    // [128 rows (gr*64+nl)][256B] swz
  const int nl = 16 * w + col;
  const int swn = (nl & 7) << 4;
#pragma unroll
  for (int t = 0; t < 16; ++t) {
    const unsigned int w0 = pk2(ot[t][0] * inv, ot[t][2] * inv);
    const unsigned int w1 = pk2(ot[t][1] * inv, ot[t][3] * inv);
    const int bo = 16 * t + 4 * q;
    *(unsigned int*)(yt + nl * 256 + (bo ^ swn)) = w0;
    *(unsigned int*)(yt + (64 + nl) * 256 + (bo ^ swn)) = w1;
  }
  __syncthreads();
  {
    const int row = tid >> 1, h2 = tid & 1;
    const int gr = row >> 6, n = row & 63;
    unsigned short* dst = yB + (((size_t)(b * 2 + gr)) * 4096 + n0 + n) * 128 + h2 * 64;
    const char* srow = yt + row * 256;
    const int sw = (n & 7) << 4;
#pragma unroll
    for (int k = 0; k < 8; ++k)
      ((uint4*)dst)[k] = *(const uint4*)(srow + ((128 * h2 + 16 * k) ^ sw));
  }
}

// ---------------------------------------------------------------------------
// Final W conv (MFMA, K=128 per group) + bias + residual.
// ---------------------------------------------------------------------------
__global__ __launch_bounds__(256)
void k_final_mfma(const float* __restrict__ x,
                  const float* __restrict__ Ww, const float* __restrict__ Wb,
                  const float* __restrict__ ws, float* __restrict__ out) {
  const int nt = blockIdx.x, gq = blockIdx.y, b = blockIdx.z;
  const int gr = gq & 1, ob = (gq >> 1) * 128;
  const int n0 = nt * 128;
  const int tid = threadIdx.x;
  const int w = tid >> 6, lane = tid & 63, q = lane >> 4, col = lane & 15;
  const unsigned short* yb = (const unsigned short*)(ws + F_Y);

  __shared__ uint4 ldsb[4096];
  char* As = (char*)ldsb;
  char* Bs = (char*)ldsb + 16384;

  f32x4 acc[2][8];
#pragma unroll
  for (int h = 0; h < 2; ++h)
#pragma unroll
    for (int j = 0; j < 8; ++j) acc[h][j] = (f32x4){0.f, 0.f, 0.f, 0.f};

  const int ro = tid >> 1, haf = tid & 1;
  for (int ks = 0; ks < 2; ++ks) {
    __syncthreads();
    {
      const float* src = Ww + (size_t)(ob + ro) * 128 + ks * 64 + haf * 32;
      char* row = As + ro * 128;
      const int sw = (ro & 7) << 4;
#pragma unroll
      for (int jj = 0; jj < 4; ++jj) {
        float4 a = ((const float4*)src)[2 * jj];
        float4 c4 = ((const float4*)src)[2 * jj + 1];
        uint4 pk;
        pk.x = pk2(a.x, a.y);  pk.y = pk2(a.z, a.w);
        pk.z = pk2(c4.x, c4.y); pk.w = pk2(c4.z, c4.w);
        *(uint4*)(row + ((haf * 64 + 16 * jj) ^ sw)) = pk;
      }
    }
    {
      const unsigned short* src = yb + (((size_t)(b * 2 + gr)) * 4096 + n0 + ro) * 128 + ks * 64 + haf * 32;
      char* row = Bs + ro * 128;
      const int sw = (ro & 7) << 4;
#pragma unroll
      for (int jj = 0; jj < 4; ++jj)
        *(uint4*)(row + ((haf * 64 + 16 * jj) ^ sw)) = ((const uint4*)src)[jj];
    }
    __syncthreads();
#pragma unroll
    for (int c = 0; c < 2; ++c) {
      bf16x8 af[2], bfr[8];
#pragma unroll
      for (int h = 0; h < 2; ++h) {
        const int r = 32 * w + 16 * h + col;
        af[h] = *(const bf16x8*)(As + r * 128 + ((64 * c + 16 * q) ^ ((r & 7) << 4)));
      }
#pragma unroll
      for (int j = 0; j < 8; ++j) {
        const int r = 16 * j + col;
        bfr[j] = *(const bf16x8*)(Bs + r * 128 + ((64 * c + 16 * q) ^ ((r & 7) << 4)));
      }
#pragma unroll
      for (int h = 0; h < 2; ++h)
#pragma unroll
        for (int j = 0; j < 8; ++j)
          acc[h][j] = __builtin_amdgcn_mfma_f32_16x16x32_bf16(af[h], bfr[j], acc[h][j], 0, 0, 0);
    }
  }

  __syncthreads();                           // reuse whole LDS: f32 [128 o][512B]
  char* ft = (char*)ldsb;
#pragma unroll
  for (int h = 0; h < 2; ++h) {
    const int o0 = 32 * w + 16 * h + 4 * q;
#pragma unroll
    for (int j = 0; j < 8; ++j) {
      const int n = 16 * j + col;
#pragma unroll
      for (int r = 0; r < 4; ++r)
        *(float*)(ft + (o0 + r) * 512 + ((n * 4) ^ (((o0 + r) & 7) << 4))) = acc[h][j][r];
    }
  }
  __syncthreads();
  {
    const int o = tid >> 1, h2 = tid & 1;
    const float bsv = Wb[ob + o];
    const int ch = 2 * (ob + o) + gr;
    const size_t base = ((size_t)(b * 512 + ch)) * 4096 + n0 + h2 * 64;
    const char* row = ft + o * 512;
    const int sw = (o & 7) << 4;
#pragma unroll
    for (int k = 0; k < 16; ++k) {
      f32x4 v = *(const f32x4*)(row + ((256 * h2 + 16 * k) ^ sw));
      float4 xv = ((const float4*)(x + base))[k];
      ((float4*)(out + base))[k] = make_float4(v[0] + bsv + xv.x, v[1] + bsv + xv.y,
                                               v[2] + bsv + xv.z, v[3] + bsv + xv.w);
    }
  }
}

extern "C" void kernel_launch(void* const* d_in, const int* in_sizes, int n_in,
                              void* d_out, int out_size, void* d_ws, size_t ws_size,
                              hipStream_t stream) {
  const float* x  = (const float*)d_in[0];
  const float* gw = (const float*)d_in[1];
  const float* gb = (const float*)d_in[2];
  const float* tw = (const float*)d_in[3];
  const float* tb = (const float*)d_in[4];
  const float* pw = (const float*)d_in[5];
  const float* pb = (const float*)d_in[6];
  const float* Ww = (const float*)d_in[7];
  const float* Wb = (const float*)d_in[8];
  float* out = (float*)d_out;
  float* ws  = (float*)d_ws;

  k_prep<<<dim3(16, 8, 8), 256, 0, stream>>>(x, ws);
  k_proj_mfma<<<dim3(32, 2, 8), 256, 0, stream>>>(tw, tb, pw, pb, ws);
  k_g_mfma<<<dim3(32, 2, 8), 256, 0, stream>>>(gw, gb, ws);
  k_attn_mfma<<<dim3(8, 64), 256, 0, stream>>>(ws);
  k_final_mfma<<<dim3(32, 4, 8), 256, 0, stream>>>(x, Ww, Wb, ws, out);
}

// Round 10
// 161.610 us; speedup vs baseline: 1.0425x; 1.0425x over previous
//
#include <hip/hip_runtime.h>

// Workspace float offsets
#define F_XM    0u          // bf16 xm[8][4096][256]      -> 4,194,304 f
#define F_XG    4194304u    // bf16 xg[8][2][4096][256]   -> 8,388,608 f
#define F_Y     4194304u    // bf16 y[8][2][4096][128] aliases xg (dead after k_g)
#define F_TH    12582912u   // bf16 theta[8][4096][128]   -> 2,097,152 f
#define F_PHIB  14680064u   // bf16 phi[8][1024][128]     ->   524,288 f
#define F_GB    15204352u   // bf16 g[8][256][1024]       -> 1,048,576 f
// total 16,252,928 floats = 65.0 MB

typedef __attribute__((ext_vector_type(4))) float f32x4;
typedef __attribute__((ext_vector_type(8))) short bf16x8;

__device__ __forceinline__ unsigned short f2bf(float f) {
  union { unsigned int i; float f; } x; x.f = f;
  unsigned int r = x.i + 0x7fffu + ((x.i >> 16) & 1u);
  return (unsigned short)(r >> 16);
}
__device__ __forceinline__ unsigned int pk2(float a, float b) {
  return (unsigned int)f2bf(a) | ((unsigned int)f2bf(b) << 16);
}
__device__ __forceinline__ void gload_lds16(const void* g, void* l) {
  __builtin_amdgcn_global_load_lds(
      (const __attribute__((address_space(1))) unsigned int*)g,
      (__attribute__((address_space(3))) unsigned int*)l, 16, 0, 0);
}

// ---------------------------------------------------------------------------
// Prep: x f32 [b][512][4096] -> bf16 xm[b][n][256] (mean over group pair) and
// xg[b][gr][n][256] (K-contiguous layouts for the MFMA GEMMs).
// ---------------------------------------------------------------------------
__global__ __launch_bounds__(256)
void k_prep(const float* __restrict__ x, float* __restrict__ ws) {
  const int nt = blockIdx.x, ct = blockIdx.y, b = blockIdx.z;
  const int n0 = nt * 256, c0 = ct * 64;
  const int tid = threadIdx.x;
  __shared__ uint4 ldsb[4096];               // 64 KB: f32 [64 c][1024B] swz
  char* lds = (char*)ldsb;
  {
    const int c = tid >> 2;
    const int nch = (tid & 3) * 64;
    const float* src = x + ((size_t)(b * 512 + c0 + c)) * 4096 + n0 + nch;
    char* row = lds + c * 1024;
    const int sw = (c & 7) << 4;
    const int bb = nch * 4;
#pragma unroll
    for (int k = 0; k < 16; ++k)
      *(uint4*)(row + ((bb + 16 * k) ^ sw)) = ((const uint4*)src)[k];
  }
  __syncthreads();
  {
    const int n = tid;
    unsigned int u0[16], u1[16], um[16];
#pragma unroll
    for (int jc = 0; jc < 4; ++jc) {
      float v[16];
#pragma unroll
      for (int cc = 0; cc < 16; ++cc) {
        const int c = 16 * jc + cc;
        v[cc] = *(const float*)(lds + c * 1024 + ((n * 4) ^ ((c & 7) << 4)));
      }
#pragma unroll
      for (int s = 0; s < 4; ++s) {
        u0[4 * jc + s] = pk2(v[4 * s], v[4 * s + 2]);
        u1[4 * jc + s] = pk2(v[4 * s + 1], v[4 * s + 3]);
        um[4 * jc + s] = pk2(0.5f * (v[4 * s] + v[4 * s + 1]),
                             0.5f * (v[4 * s + 2] + v[4 * s + 3]));
      }
    }
    unsigned short* xm = (unsigned short*)(ws + F_XM);
    unsigned short* xg = (unsigned short*)(ws + F_XG);
    uint4* d0 = (uint4*)(xg + (((size_t)(b * 2 + 0) * 4096) + n0 + n) * 256 + (c0 >> 1));
    uint4* d1 = (uint4*)(xg + (((size_t)(b * 2 + 1) * 4096) + n0 + n) * 256 + (c0 >> 1));
    uint4* dm = (uint4*)(xm + ((size_t)(b * 4096) + n0 + n) * 256 + (c0 >> 1));
#pragma unroll
    for (int s = 0; s < 4; ++s) {
      d0[s] = make_uint4(u0[4 * s], u0[4 * s + 1], u0[4 * s + 2], u0[4 * s + 3]);
      d1[s] = make_uint4(u1[4 * s], u1[4 * s + 1], u1[4 * s + 2], u1[4 * s + 3]);
      dm[s] = make_uint4(um[4 * s], um[4 * s + 1], um[4 * s + 2], um[4 * s + 3]);
    }
  }
}

// ---------------------------------------------------------------------------
// theta & phi projections from xm (K=256). Out tile 128 o x 128 n, 4 waves.
// ot=0: theta[b][n][o] bf16 (LDS transpose). ot=1: pooled phiB[b][m][o] bf16.
// ---------------------------------------------------------------------------
__global__ __launch_bounds__(256)
void k_proj_mfma(const float* __restrict__ tw, const float* __restrict__ tb,
                 const float* __restrict__ pw, const float* __restrict__ pb,
                 float* __restrict__ ws) {
  const int nt = blockIdx.x, ot = blockIdx.y, b = blockIdx.z;
  const int n0 = nt * 128;
  const int tid = threadIdx.x;
  const int w = tid >> 6, lane = tid & 63, q = lane >> 4, col = lane & 15;
  const float* W = ot ? pw : tw;
  const float* bias = ot ? pb : tb;
  const unsigned short* xm = (const unsigned short*)(ws + F_XM);

  __shared__ uint4 ldsb[4096];               // 64 KB
  char* Ws = (char*)ldsb;                    // [128 o][128B] swz
  char* Xs = (char*)ldsb + 16384;            // [128 n][128B] swz

  f32x4 acc[2][8];
#pragma unroll
  for (int h = 0; h < 2; ++h)
#pragma unroll
    for (int j = 0; j < 8; ++j) acc[h][j] = (f32x4){0.f, 0.f, 0.f, 0.f};

  const int ro = tid >> 1, haf = tid & 1;
  for (int ks = 0; ks < 4; ++ks) {
    __syncthreads();
    {
      const float* src = W + (size_t)ro * 256 + ks * 64 + haf * 32;
      char* row = Ws + ro * 128;
      const int sw = (ro & 7) << 4;
#pragma unroll
      for (int jj = 0; jj < 4; ++jj) {
        float4 a = ((const float4*)src)[2 * jj];
        float4 c4 = ((const float4*)src)[2 * jj + 1];
        uint4 pk;
        pk.x = pk2(a.x, a.y);  pk.y = pk2(a.z, a.w);
        pk.z = pk2(c4.x, c4.y); pk.w = pk2(c4.z, c4.w);
        *(uint4*)(row + ((haf * 64 + 16 * jj) ^ sw)) = pk;
      }
    }
    {
      const unsigned short* src = xm + ((size_t)(b * 4096) + n0 + ro) * 256 + ks * 64 + haf * 32;
      char* row = Xs + ro * 128;
      const int sw = (ro & 7) << 4;
#pragma unroll
      for (int jj = 0; jj < 4; ++jj)
        *(uint4*)(row + ((haf * 64 + 16 * jj) ^ sw)) = ((const uint4*)src)[jj];
    }
    __syncthreads();
#pragma unroll
    for (int c = 0; c < 2; ++c) {
      bf16x8 af[2], bfr[8];
#pragma unroll
      for (int h = 0; h < 2; ++h) {
        const int r = 32 * w + 16 * h + col;
        af[h] = *(const bf16x8*)(Ws + r * 128 + ((64 * c + 16 * q) ^ ((r & 7) << 4)));
      }
#pragma unroll
      for (int j = 0; j < 8; ++j) {
        const int r = 16 * j + col;
        bfr[j] = *(const bf16x8*)(Xs + r * 128 + ((64 * c + 16 * q) ^ ((r & 7) << 4)));
      }
#pragma unroll
      for (int h = 0; h < 2; ++h)
#pragma unroll
        for (int j = 0; j < 8; ++j)
          acc[h][j] = __builtin_amdgcn_mfma_f32_16x16x32_bf16(af[h], bfr[j], acc[h][j], 0, 0, 0);
    }
  }

  float bs[2][4];
#pragma unroll
  for (int h = 0; h < 2; ++h) {
    const int o0 = 32 * w + 16 * h + 4 * q;
#pragma unroll
    for (int r = 0; r < 4; ++r) bs[h][r] = bias[o0 + r];
  }

  if (ot == 0) {
    char* trb = (char*)ldsb + 32768;         // [128 n][256B] swz, fresh region
#pragma unroll
    for (int h = 0; h < 2; ++h) {
      const int o0 = 32 * w + 16 * h + 4 * q;
#pragma unroll
      for (int j = 0; j < 8; ++j) {
        const int n = 16 * j + col;
        uint2 pkk = make_uint2(pk2(acc[h][j][0] + bs[h][0], acc[h][j][1] + bs[h][1]),
                               pk2(acc[h][j][2] + bs[h][2], acc[h][j][3] + bs[h][3]));
        *(uint2*)(trb + n * 256 + ((2 * o0) ^ ((n & 7) << 4))) = pkk;
      }
    }
    __syncthreads();
    {
      const int n = tid >> 1, h2 = tid & 1;
      unsigned short* dst = (unsigned short*)(ws + F_TH) + ((size_t)(b * 4096) + n0 + n) * 128 + h2 * 64;
      const char* row = trb + n * 256;
      const int sw = (n & 7) << 4;
#pragma unroll
      for (int k = 0; k < 8; ++k)
        ((uint4*)dst)[k] = *(const uint4*)(row + ((128 * h2 + 16 * k) ^ sw));
    }
  } else {
    const int mb = (nt >> 3) * 256 + (nt & 7) * 32;
    unsigned short* phiB = (unsigned short*)(ws + F_PHIB);
#pragma unroll
    for (int h = 0; h < 2; ++h) {
      const int o0 = 32 * w + 16 * h + 4 * q;
#pragma unroll
      for (int jj = 0; jj < 4; ++jj) {
        const int j = (jj >> 1) * 4 + (jj & 1);   // {0,1,4,5}
        f32x4 pm;
#pragma unroll
        for (int r = 0; r < 4; ++r)
          pm[r] = fmaxf(acc[h][j][r], acc[h][j + 2][r]);
#pragma unroll
        for (int r = 0; r < 4; ++r)
          pm[r] = fmaxf(pm[r], __shfl_xor(pm[r], 1));
        if ((col & 1) == 0) {
          const int vp = 8 * (j & 1) + (col >> 1);
          const int m = mb + 16 * (j >> 2) + vp;
          uint2 pkk = make_uint2(pk2(pm[0] + bs[h][0], pm[1] + bs[h][1]),
                                 pk2(pm[2] + bs[h][2], pm[3] + bs[h][3]));
          *(uint2*)(phiB + ((size_t)(b * 1024) + m) * 128 + o0) = pkk;
        }
      }
    }
  }
}

// ---------------------------------------------------------------------------
// g projection from xg (per group, K=256), fused pool -> gB[b][d=2o+gr][m].
// ---------------------------------------------------------------------------
__global__ __launch_bounds__(256)
void k_g_mfma(const float* __restrict__ gw, const float* __restrict__ gb,
              float* __restrict__ ws) {
  const int nt = blockIdx.x, gr = blockIdx.y, b = blockIdx.z;
  const int n0 = nt * 128;
  const int tid = threadIdx.x;
  const int w = tid >> 6, lane = tid & 63, q = lane >> 4, col = lane & 15;
  const unsigned short* xg = (const unsigned short*)(ws + F_XG);

  __shared__ uint4 ldsb[4096];
  char* Ws = (char*)ldsb;
  char* Xs = (char*)ldsb + 16384;

  f32x4 acc[2][8];
#pragma unroll
  for (int h = 0; h < 2; ++h)
#pragma unroll
    for (int j = 0; j < 8; ++j) acc[h][j] = (f32x4){0.f, 0.f, 0.f, 0.f};

  const int ro = tid >> 1, haf = tid & 1;
  for (int ks = 0; ks < 4; ++ks) {
    __syncthreads();
    {
      const float* src = gw + (size_t)ro * 256 + ks * 64 + haf * 32;
      char* row = Ws + ro * 128;
      const int sw = (ro & 7) << 4;
#pragma unroll
      for (int jj = 0; jj < 4; ++jj) {
        float4 a = ((const float4*)src)[2 * jj];
        float4 c4 = ((const float4*)src)[2 * jj + 1];
        uint4 pk;
        pk.x = pk2(a.x, a.y);  pk.y = pk2(a.z, a.w);
        pk.z = pk2(c4.x, c4.y); pk.w = pk2(c4.z, c4.w);
        *(uint4*)(row + ((haf * 64 + 16 * jj) ^ sw)) = pk;
      }
    }
    {
      const unsigned short* src = xg + (((size_t)(b * 2 + gr)) * 4096 + n0 + ro) * 256 + ks * 64 + haf * 32;
      char* row = Xs + ro * 128;
      const int sw = (ro & 7) << 4;
#pragma unroll
      for (int jj = 0; jj < 4; ++jj)
        *(uint4*)(row + ((haf * 64 + 16 * jj) ^ sw)) = ((const uint4*)src)[jj];
    }
    __syncthreads();
#pragma unroll
    for (int c = 0; c < 2; ++c) {
      bf16x8 af[2], bfr[8];
#pragma unroll
      for (int h = 0; h < 2; ++h) {
        const int r = 32 * w + 16 * h + col;
        af[h] = *(const bf16x8*)(Ws + r * 128 + ((64 * c + 16 * q) ^ ((r & 7) << 4)));
      }
#pragma unroll
      for (int j = 0; j < 8; ++j) {
        const int r = 16 * j + col;
        bfr[j] = *(const bf16x8*)(Xs + r * 128 + ((64 * c + 16 * q) ^ ((r & 7) << 4)));
      }
#pragma unroll
      for (int h = 0; h < 2; ++h)
#pragma unroll
        for (int j = 0; j < 8; ++j)
          acc[h][j] = __builtin_amdgcn_mfma_f32_16x16x32_bf16(af[h], bfr[j], acc[h][j], 0, 0, 0);
    }
  }

  const int mb = (nt >> 3) * 256 + (nt & 7) * 32;
  char* pt = (char*)ldsb + 32768;            // [128 o][80B], fresh region
#pragma unroll
  for (int h = 0; h < 2; ++h) {
    const int o0 = 32 * w + 16 * h + 4 * q;
#pragma unroll
    for (int jj = 0; jj < 4; ++jj) {
      const int j = (jj >> 1) * 4 + (jj & 1);
      f32x4 pm;
#pragma unroll
      for (int r = 0; r < 4; ++r)
        pm[r] = fmaxf(acc[h][j][r], acc[h][j + 2][r]);
#pragma unroll
      for (int r = 0; r < 4; ++r)
        pm[r] = fmaxf(pm[r], __shfl_xor(pm[r], 1));
      if ((col & 1) == 0) {
        const int ml = 16 * (j >> 2) + 8 * (j & 1) + (col >> 1);
#pragma unroll
        for (int r = 0; r < 4; ++r)
          *(unsigned short*)(pt + (o0 + r) * 80 + ml * 2) = f2bf(pm[r] + gb[o0 + r]);
      }
    }
  }
  __syncthreads();
  if (tid < 128) {
    const int o = tid;
    const char* row = pt + o * 80;
    unsigned short* dst = (unsigned short*)(ws + F_GB) + ((size_t)(b * 256) + 2 * o + gr) * 1024 + mb;
#pragma unroll
    for (int k = 0; k < 4; ++k)
      ((uint4*)dst)[k] = *(const uint4*)(row + 16 * k);
  }
}

// ---------------------------------------------------------------------------
// MFMA flash attention v7: 8 waves / 128 n-rows per block (halves staging
// traffic), dbuf global_load_lds (K 2x8KB per-iter, V 2x32KB 128B-row pairs),
// P repack via per-wave LDS (R8 form). One barrier/iter. LDS 96KB, 1 blk/CU.
// ---------------------------------------------------------------------------
#define KVB 32
#define NIT 32
__global__ __launch_bounds__(512)
void k_attn_mfma(float* __restrict__ ws) {
  const int b = blockIdx.x;          // 8 batches -> 8 XCDs (round-robin)
  const int n0 = blockIdx.y * 128;
  const int tid = threadIdx.x;
  const int w = tid >> 6;            // 0..7
  const int lane = tid & 63;
  const int q = lane >> 4;
  const int col = lane & 15;
  const int ksw = (col & 7) << 4;

  __shared__ char lds[98304];
  // kbuf[2]: 2 x 8KB  @ 0      (K tile [32 m][256B], row-swz ((m&7)<<4))
  // vbuf[2]: 2 x 32KB @ 16384  (V^T pair-tile [256 d][128B], row-swz ((d&7)<<4))
  // pl     : 8 x 2KB  @ 81920  (per-wave P)
  char* plw = lds + 81920 + w * 2048;

  const unsigned short* thetaB = (const unsigned short*)(ws + F_TH);
  const char* phiBb = (const char*)((const unsigned short*)(ws + F_PHIB) + (size_t)b * 1024 * 128);
  const char* gBb   = (const char*)((const unsigned short*)(ws + F_GB) + (size_t)b * 256 * 1024);
  unsigned short* yB = (unsigned short*)(ws + F_Y);

  // staging geometry (pre-swizzled global SOURCE, linear LDS dest = base+lane*16)
  const int kr0 = lane >> 4;               // K: row within 4-row chunk
  const int kso = (lane & 15) * 16;        // K: byte within 256B row
  const int vr0 = lane >> 3;               // V: row within 8-row chunk
  const int vso = (lane & 7) * 16;         // V: byte within 128B row

  bf16x8 qf[4];
  {
    const unsigned short* qp = thetaB + ((size_t)(b * 4096 + n0 + 16 * w + col)) * 128 + 8 * q;
#pragma unroll
    for (int c = 0; c < 4; ++c) qf[c] = *(const bf16x8*)(qp + 32 * c);
  }

  f32x4 ot[16];
#pragma unroll
  for (int t = 0; t < 16; ++t) ot[t] = (f32x4){0.f, 0.f, 0.f, 0.f};
  float mrun = -1e30f, lsum = 0.f;

  // prologue: K tile 0 -> kbuf0 (chunk w), V pair 0 -> vbuf0 (chunks 4w..4w+3)
  {
    const int r = 4 * w + kr0;
    gload_lds16(phiBb + (size_t)r * 256 + (kso ^ ((r & 7) << 4)), lds + w * 1024);
#pragma unroll
    for (int j = 0; j < 4; ++j) {
      const int c = 4 * w + j;
      const int d = 8 * c + vr0;
      gload_lds16(gBb + (size_t)d * 2048 + (vso ^ ((d & 7) << 4)),
                  lds + 16384 + c * 1024);
    }
  }
  __syncthreads();

  for (int mt = 0; mt < NIT; ++mt) {
    char* ktc = lds + (mt & 1) * 8192;
    char* vtc = lds + 16384 + ((mt >> 1) & 1) * 32768;
    const int par = mt & 1;

    // stage next K tile (async; completes by end-of-iter barrier)
    if (mt + 1 < NIT) {
      const size_t moff = (size_t)(mt + 1) * KVB;
      const int r = 4 * w + kr0;
      gload_lds16(phiBb + (moff + r) * 256 + (kso ^ ((r & 7) << 4)),
                  lds + ((mt & 1) ^ 1) * 8192 + w * 1024);
    }
    // stage next V pair at pair boundary
    if (par == 0 && mt + 2 < NIT) {
      const size_t pm0 = (size_t)((mt >> 1) + 1) * 64;
#pragma unroll
      for (int j = 0; j < 4; ++j) {
        const int c = 4 * w + j;
        const int d = 8 * c + vr0;
        gload_lds16(gBb + (size_t)d * 2048 + pm0 * 2 + (vso ^ ((d & 7) << 4)),
                    lds + 16384 + (((mt >> 1) & 1) ^ 1) * 32768 + c * 1024);
      }
    }

    // S^T = K . Q^T  (st[s]: m-local 16s..16s+15, n = col)
    f32x4 st[2];
#pragma unroll
    for (int s = 0; s < 2; ++s) st[s] = (f32x4){0.f, 0.f, 0.f, 0.f};
    __builtin_amdgcn_s_setprio(1);
#pragma unroll
    for (int c = 0; c < 4; ++c)
#pragma unroll
      for (int s = 0; s < 2; ++s) {
        const bf16x8 kf = *(const bf16x8*)(ktc + (16 * s + col) * 256 +
                                           ((64 * c + 16 * q) ^ ksw));
        st[s] = __builtin_amdgcn_mfma_f32_16x16x32_bf16(kf, qf[c], st[s], 0, 0, 0);
      }
    __builtin_amdgcn_s_setprio(0);

    // online softmax with defer-max (threshold 8)
    float pmax = -1e30f;
#pragma unroll
    for (int s = 0; s < 2; ++s)
#pragma unroll
      for (int r = 0; r < 4; ++r) pmax = fmaxf(pmax, st[s][r]);
    pmax = fmaxf(pmax, __shfl_xor(pmax, 16));
    pmax = fmaxf(pmax, __shfl_xor(pmax, 32));
    if (!__all(pmax - mrun <= 8.f)) {
      const float mnew = fmaxf(mrun, pmax);
      const float scl = __expf(mrun - mnew);
      mrun = mnew;
      lsum *= scl;
#pragma unroll
      for (int t = 0; t < 16; ++t) {
        ot[t][0] *= scl; ot[t][1] *= scl; ot[t][2] *= scl; ot[t][3] *= scl;
      }
    }
    float rsum = 0.f;
#pragma unroll
    for (int s = 0; s < 2; ++s)
#pragma unroll
      for (int r = 0; r < 4; ++r) {
        st[s][r] = __expf(st[s][r] - mrun);
        rsum += st[s][r];
      }
    rsum += __shfl_xor(rsum, 16);
    rsum += __shfl_xor(rsum, 32);
    lsum += rsum;

    // P -> bf16 -> wave-private LDS -> one B-fragment (m=32)
    char* prow = plw + col * 128;
#pragma unroll
    for (int s = 0; s < 2; ++s)
#pragma unroll
      for (int h = 0; h < 2; ++h)
        *(unsigned int*)(prow + ((32 * s + 8 * q + 4 * h) ^ ksw)) =
            pk2(st[s][2 * h], st[s][2 * h + 1]);
    const bf16x8 pf = *(const bf16x8*)(prow + ((16 * q) ^ ksw));

    // O^T += V^T . P^T  (V pair-tile: 64B half selected by par)
    __builtin_amdgcn_s_setprio(1);
#pragma unroll
    for (int t = 0; t < 16; ++t) {
      const int d = 16 * t + col;
      const bf16x8 vf = *(const bf16x8*)(vtc + d * 128 +
                                         ((64 * par + 16 * q) ^ ((d & 7) << 4)));
      ot[t] = __builtin_amdgcn_mfma_f32_16x16x32_bf16(vf, pf, ot[t], 0, 0, 0);
    }
    __builtin_amdgcn_s_setprio(0);

    __syncthreads();   // staged tiles complete + all waves done with cur bufs
  }

  // epilogue: y[b][gr][n][i] bf16. d = 16t+4q+r -> gr=r&1, i = 8t+2q+(r>>1)
  const float inv = 1.f / lsum;
  char* yt = lds;                    // [256 rows (gr*128+nl)][256B] swz (64KB)
  const int nl = 16 * w + col;
  const int swn = (nl & 7) << 4;
#pragma unroll
  for (int t = 0; t < 16; ++t) {
    const unsigned int w0 = pk2(ot[t][0] * inv, ot[t][2] * inv);
    const unsigned int w1 = pk2(ot[t][1] * inv, ot[t][3] * inv);
    const int bo = 16 * t + 4 * q;
    *(unsigned int*)(yt + nl * 256 + (bo ^ swn)) = w0;
    *(unsigned int*)(yt + (128 + nl) * 256 + (bo ^ swn)) = w1;
  }
  __syncthreads();
  {
    const int row = tid >> 1, h2 = tid & 1;
    const int gr = row >> 7, n = row & 127;
    unsigned short* dst = yB + (((size_t)(b * 2 + gr)) * 4096 + n0 + n) * 128 + h2 * 64;
    const char* srow = yt + row * 256;
    const int sw = (n & 7) << 4;
#pragma unroll
    for (int k = 0; k < 8; ++k)
      ((uint4*)dst)[k] = *(const uint4*)(srow + ((128 * h2 + 16 * k) ^ sw));
  }
}

// ---------------------------------------------------------------------------
// Final W conv (MFMA, K=128 per group) + bias + residual.
// ---------------------------------------------------------------------------
__global__ __launch_bounds__(256)
void k_final_mfma(const float* __restrict__ x,
                  const float* __restrict__ Ww, const float* __restrict__ Wb,
                  const float* __restrict__ ws, float* __restrict__ out) {
  const int nt = blockIdx.x, gq = blockIdx.y, b = blockIdx.z;
  const int gr = gq & 1, ob = (gq >> 1) * 128;
  const int n0 = nt * 128;
  const int tid = threadIdx.x;
  const int w = tid >> 6, lane = tid & 63, q = lane >> 4, col = lane & 15;
  const unsigned short* yb = (const unsigned short*)(ws + F_Y);

  __shared__ uint4 ldsb[4096];
  char* As = (char*)ldsb;
  char* Bs = (char*)ldsb + 16384;

  f32x4 acc[2][8];
#pragma unroll
  for (int h = 0; h < 2; ++h)
#pragma unroll
    for (int j = 0; j < 8; ++j) acc[h][j] = (f32x4){0.f, 0.f, 0.f, 0.f};

  const int ro = tid >> 1, haf = tid & 1;
  for (int ks = 0; ks < 2; ++ks) {
    __syncthreads();
    {
      const float* src = Ww + (size_t)(ob + ro) * 128 + ks * 64 + haf * 32;
      char* row = As + ro * 128;
      const int sw = (ro & 7) << 4;
#pragma unroll
      for (int jj = 0; jj < 4; ++jj) {
        float4 a = ((const float4*)src)[2 * jj];
        float4 c4 = ((const float4*)src)[2 * jj + 1];
        uint4 pk;
        pk.x = pk2(a.x, a.y);  pk.y = pk2(a.z, a.w);
        pk.z = pk2(c4.x, c4.y); pk.w = pk2(c4.z, c4.w);
        *(uint4*)(row + ((haf * 64 + 16 * jj) ^ sw)) = pk;
      }
    }
    {
      const unsigned short* src = yb + (((size_t)(b * 2 + gr)) * 4096 + n0 + ro) * 128 + ks * 64 + haf * 32;
      char* row = Bs + ro * 128;
      const int sw = (ro & 7) << 4;
#pragma unroll
      for (int jj = 0; jj < 4; ++jj)
        *(uint4*)(row + ((haf * 64 + 16 * jj) ^ sw)) = ((const uint4*)src)[jj];
    }
    __syncthreads();
#pragma unroll
    for (int c = 0; c < 2; ++c) {
      bf16x8 af[2], bfr[8];
#pragma unroll
      for (int h = 0; h < 2; ++h) {
        const int r = 32 * w + 16 * h + col;
        af[h] = *(const bf16x8*)(As + r * 128 + ((64 * c + 16 * q) ^ ((r & 7) << 4)));
      }
#pragma unroll
      for (int j = 0; j < 8; ++j) {
        const int r = 16 * j + col;
        bfr[j] = *(const bf16x8*)(Bs + r * 128 + ((64 * c + 16 * q) ^ ((r & 7) << 4)));
      }
#pragma unroll
      for (int h = 0; h < 2; ++h)
#pragma unroll
        for (int j = 0; j < 8; ++j)
          acc[h][j] = __builtin_amdgcn_mfma_f32_16x16x32_bf16(af[h], bfr[j], acc[h][j], 0, 0, 0);
    }
  }

  __syncthreads();                           // reuse whole LDS: f32 [128 o][512B]
  char* ft = (char*)ldsb;
#pragma unroll
  for (int h = 0; h < 2; ++h) {
    const int o0 = 32 * w + 16 * h + 4 * q;
#pragma unroll
    for (int j = 0; j < 8; ++j) {
      const int n = 16 * j + col;
#pragma unroll
      for (int r = 0; r < 4; ++r)
        *(float*)(ft + (o0 + r) * 512 + ((n * 4) ^ (((o0 + r) & 7) << 4))) = acc[h][j][r];
    }
  }
  __syncthreads();
  {
    const int o = tid >> 1, h2 = tid & 1;
    const float bsv = Wb[ob + o];
    const int ch = 2 * (ob + o) + gr;
    const size_t base = ((size_t)(b * 512 + ch)) * 4096 + n0 + h2 * 64;
    const char* row = ft + o * 512;
    const int sw = (o & 7) << 4;
#pragma unroll
    for (int k = 0; k < 16; ++k) {
      f32x4 v = *(const f32x4*)(row + ((256 * h2 + 16 * k) ^ sw));
      float4 xv = ((const float4*)(x + base))[k];
      ((float4*)(out + base))[k] = make_float4(v[0] + bsv + xv.x, v[1] + bsv + xv.y,
                                               v[2] + bsv + xv.z, v[3] + bsv + xv.w);
    }
  }
}

extern "C" void kernel_launch(void* const* d_in, const int* in_sizes, int n_in,
                              void* d_out, int out_size, void* d_ws, size_t ws_size,
                              hipStream_t stream) {
  const float* x  = (const float*)d_in[0];
  const float* gw = (const float*)d_in[1];
  const float* gb = (const float*)d_in[2];
  const float* tw = (const float*)d_in[3];
  const float* tb = (const float*)d_in[4];
  const float* pw = (const float*)d_in[5];
  const float* pb = (const float*)d_in[6];
  const float* Ww = (const float*)d_in[7];
  const float* Wb = (const float*)d_in[8];
  float* out = (float*)d_out;
  float* ws  = (float*)d_ws;

  k_prep<<<dim3(16, 8, 8), 256, 0, stream>>>(x, ws);
  k_proj_mfma<<<dim3(32, 2, 8), 256, 0, stream>>>(tw, tb, pw, pb, ws);
  k_g_mfma<<<dim3(32, 2, 8), 256, 0, stream>>>(gw, gb, ws);
  k_attn_mfma<<<dim3(8, 32), 512, 0, stream>>>(ws);
  k_final_mfma<<<dim3(32, 4, 8), 256, 0, stream>>>(x, Ww, Wb, ws, out);
}